// Round 1
// baseline (247.288 us; speedup 1.0000x reference)
//
#include <hip/hip_runtime.h>
#include <hip/hip_bf16.h>
#include <math.h>

typedef __bf16 bf16;
typedef __bf16 v8bf __attribute__((ext_vector_type(8)));
typedef __bf16 v4bf __attribute__((ext_vector_type(4)));
typedef float f32x4 __attribute__((ext_vector_type(4)));

#define L_SEQ 4096
#define DMODEL 1024
#define NHEADS 16
#define DH 64
#define NEG_BIG (-1e30f)
#define LN1E4_64 0.14391156f   // ln(10000)/64
#define SCL2 0.18033688f       // 0.125 * log2(e): scores scaled into log2 domain

// ---------------------------------------------------------------------------
// One-shot f32 -> bf16 conversion. Layout: xb[4096*1024], wqkvb[1536*1024]
// (Wq rows 0..1023, Wk rows 1024..1279, Wv rows 1280..1535), wob[1024*1024].
// ---------------------------------------------------------------------------
__global__ void convert_all(const float* __restrict__ x, const float* __restrict__ wq,
                            const float* __restrict__ wk, const float* __restrict__ wv,
                            const float* __restrict__ wo,
                            bf16* __restrict__ xb, bf16* __restrict__ wqkvb,
                            bf16* __restrict__ wob) {
    int i = (blockIdx.x * 256 + threadIdx.x) * 4;
    const float* src;
    bf16* dst;
    if (i < 4194304)      { src = x  + i;             dst = xb    + i; }
    else if (i < 5242880) { src = wq + (i - 4194304); dst = wqkvb + (i - 4194304); }
    else if (i < 5505024) { src = wk + (i - 5242880); dst = wqkvb + 1048576 + (i - 5242880); }
    else if (i < 5767168) { src = wv + (i - 5505024); dst = wqkvb + 1310720 + (i - 5505024); }
    else                  { src = wo + (i - 5767168); dst = wob   + (i - 5767168); }
    f32x4 v = *(const f32x4*)src;
    v4bf r;
#pragma unroll
    for (int j = 0; j < 4; j++) r[j] = (bf16)v[j];
    *(v4bf*)dst = r;
}

// ---------------------------------------------------------------------------
// Fused QKV projection: C[4096][1536] = x @ [Wq;Wk;Wv]^T, 128x128 tiles,
// 512 threads (8 waves, 2 waves/SIMD), register-prefetch pipeline.
// Epilogue by column region: Q (+RoPE) -> Qb, K (+RoPE) -> Kb, V -> Vtg^T.
// ---------------------------------------------------------------------------
__global__ __launch_bounds__(512) void gemm_qkv(const bf16* __restrict__ A,
                                                const bf16* __restrict__ W,
                                                bf16* __restrict__ Qb,
                                                bf16* __restrict__ Kb,
                                                bf16* __restrict__ Vtg,
                                                const int* __restrict__ tp) {
    __shared__ bf16 As[128][68];
    __shared__ bf16 Bs[128][68];
    const int K = 1024;
    const int tid = threadIdx.x;
    const int w = tid >> 6, lane = tid & 63;
    const int quad = lane >> 4, l16 = lane & 15;
    const int wm = (w & 1) * 64, wn = (w >> 1) * 32;
    const int bm = blockIdx.y * 128, bn = blockIdx.x * 128;

    f32x4 acc[4][2];
#pragma unroll
    for (int mf = 0; mf < 4; mf++)
#pragma unroll
        for (int nf = 0; nf < 2; nf++) acc[mf][nf] = (f32x4){0.f, 0.f, 0.f, 0.f};

    const int sr = tid >> 2;          // 0..127
    const int scb = (tid & 3) * 16;   // 0,16,32,48

    v8bf pa0, pa1, pb0, pb1;
    {   // prologue: stage tile kt=0
        const bf16* ap = &A[(size_t)(bm + sr) * K + scb];
        const bf16* bp = &W[(size_t)(bn + sr) * K + scb];
        pa0 = *(const v8bf*)ap; pa1 = *(const v8bf*)(ap + 8);
        pb0 = *(const v8bf*)bp; pb1 = *(const v8bf*)(bp + 8);
        *(v8bf*)&As[sr][scb] = pa0; *(v8bf*)&As[sr][scb + 8] = pa1;
        *(v8bf*)&Bs[sr][scb] = pb0; *(v8bf*)&Bs[sr][scb + 8] = pb1;
    }

    for (int kt = 0; kt < K; kt += 64) {
        __syncthreads();
        const bool more = (kt + 64) < K;
        if (more) {
            const bf16* ap = &A[(size_t)(bm + sr) * K + kt + 64 + scb];
            const bf16* bp = &W[(size_t)(bn + sr) * K + kt + 64 + scb];
            pa0 = *(const v8bf*)ap; pa1 = *(const v8bf*)(ap + 8);
            pb0 = *(const v8bf*)bp; pb1 = *(const v8bf*)(bp + 8);
        }
#pragma unroll
        for (int kf = 0; kf < 2; kf++) {
            v8bf a[4], b[2];
#pragma unroll
            for (int mf = 0; mf < 4; mf++) a[mf] = *(v8bf*)&As[wm + mf * 16 + l16][kf * 32 + quad * 8];
#pragma unroll
            for (int nf = 0; nf < 2; nf++) b[nf] = *(v8bf*)&Bs[wn + nf * 16 + l16][kf * 32 + quad * 8];
#pragma unroll
            for (int mf = 0; mf < 4; mf++)
#pragma unroll
                for (int nf = 0; nf < 2; nf++)
                    acc[mf][nf] = __builtin_amdgcn_mfma_f32_16x16x32_bf16(a[mf], b[nf], acc[mf][nf], 0, 0, 0);
        }
        __syncthreads();
        if (more) {
            *(v8bf*)&As[sr][scb] = pa0; *(v8bf*)&As[sr][scb + 8] = pa1;
            *(v8bf*)&Bs[sr][scb] = pb0; *(v8bf*)&Bs[sr][scb + 8] = pb1;
        }
    }

    if (bn < 1024) {          // ---- Q region: RoPE, store Qb[row][col] ----
#pragma unroll
        for (int mf = 0; mf < 4; mf++) {
            int pos_[4];
#pragma unroll
            for (int r = 0; r < 4; r++) pos_[r] = tp[bm + wm + mf * 16 + quad * 4 + r];
#pragma unroll
            for (int nf = 0; nf < 2; nf++) {
                const int col = bn + wn + nf * 16 + l16;
                float fr = __expf(-(float)((col & 63) & ~1) * LN1E4_64);
#pragma unroll
                for (int r = 0; r < 4; r++) {
                    float v = acc[mf][nf][r];
                    float sn, cs;
                    __sincosf((float)pos_[r] * fr, &sn, &cs);
                    float p = __shfl_xor(v, 1);
                    float res = (l16 & 1) ? (p * sn + v * cs) : (v * cs - p * sn);
                    int row = bm + wm + mf * 16 + quad * 4 + r;
                    Qb[(size_t)row * DMODEL + col] = (bf16)res;
                }
            }
        }
    } else if (bn < 1280) {   // ---- K region: RoPE, store Kb[row][kcol] ----
#pragma unroll
        for (int mf = 0; mf < 4; mf++) {
            int pos_[4];
#pragma unroll
            for (int r = 0; r < 4; r++) pos_[r] = tp[bm + wm + mf * 16 + quad * 4 + r];
#pragma unroll
            for (int nf = 0; nf < 2; nf++) {
                const int kcol = bn - 1024 + wn + nf * 16 + l16;
                float fr = __expf(-(float)((kcol & 63) & ~1) * LN1E4_64);
#pragma unroll
                for (int r = 0; r < 4; r++) {
                    float v = acc[mf][nf][r];
                    float sn, cs;
                    __sincosf((float)pos_[r] * fr, &sn, &cs);
                    float p = __shfl_xor(v, 1);
                    float res = (l16 & 1) ? (p * sn + v * cs) : (v * cs - p * sn);
                    int row = bm + wm + mf * 16 + quad * 4 + r;
                    Kb[(size_t)row * 256 + kcol] = (bf16)res;
                }
            }
        }
    } else {                  // ---- V region: transposed store Vtg[vcol][row] ----
#pragma unroll
        for (int mf = 0; mf < 4; mf++)
#pragma unroll
            for (int nf = 0; nf < 2; nf++) {
                v4bf pk;
#pragma unroll
                for (int r = 0; r < 4; r++) pk[r] = (bf16)acc[mf][nf][r];
                int vcol = bn - 1280 + wn + nf * 16 + l16;
                int row = bm + wm + mf * 16 + quad * 4;
                *(v4bf*)&Vtg[(size_t)vcol * L_SEQ + row] = pk;
            }
    }
}

// ---------------------------------------------------------------------------
// Output projection: out[4096][1024] = Attn @ Wo^T, f32 out. Same engine.
// ---------------------------------------------------------------------------
__global__ __launch_bounds__(512) void gemm_out(const bf16* __restrict__ A,
                                                const bf16* __restrict__ W,
                                                float* __restrict__ C) {
    __shared__ bf16 As[128][68];
    __shared__ bf16 Bs[128][68];
    const int K = 1024, N = 1024;
    const int tid = threadIdx.x;
    const int w = tid >> 6, lane = tid & 63;
    const int quad = lane >> 4, l16 = lane & 15;
    const int wm = (w & 1) * 64, wn = (w >> 1) * 32;
    const int bm = blockIdx.y * 128, bn = blockIdx.x * 128;

    f32x4 acc[4][2];
#pragma unroll
    for (int mf = 0; mf < 4; mf++)
#pragma unroll
        for (int nf = 0; nf < 2; nf++) acc[mf][nf] = (f32x4){0.f, 0.f, 0.f, 0.f};

    const int sr = tid >> 2;
    const int scb = (tid & 3) * 16;

    v8bf pa0, pa1, pb0, pb1;
    {
        const bf16* ap = &A[(size_t)(bm + sr) * K + scb];
        const bf16* bp = &W[(size_t)(bn + sr) * K + scb];
        pa0 = *(const v8bf*)ap; pa1 = *(const v8bf*)(ap + 8);
        pb0 = *(const v8bf*)bp; pb1 = *(const v8bf*)(bp + 8);
        *(v8bf*)&As[sr][scb] = pa0; *(v8bf*)&As[sr][scb + 8] = pa1;
        *(v8bf*)&Bs[sr][scb] = pb0; *(v8bf*)&Bs[sr][scb + 8] = pb1;
    }

    for (int kt = 0; kt < K; kt += 64) {
        __syncthreads();
        const bool more = (kt + 64) < K;
        if (more) {
            const bf16* ap = &A[(size_t)(bm + sr) * K + kt + 64 + scb];
            const bf16* bp = &W[(size_t)(bn + sr) * K + kt + 64 + scb];
            pa0 = *(const v8bf*)ap; pa1 = *(const v8bf*)(ap + 8);
            pb0 = *(const v8bf*)bp; pb1 = *(const v8bf*)(bp + 8);
        }
#pragma unroll
        for (int kf = 0; kf < 2; kf++) {
            v8bf a[4], b[2];
#pragma unroll
            for (int mf = 0; mf < 4; mf++) a[mf] = *(v8bf*)&As[wm + mf * 16 + l16][kf * 32 + quad * 8];
#pragma unroll
            for (int nf = 0; nf < 2; nf++) b[nf] = *(v8bf*)&Bs[wn + nf * 16 + l16][kf * 32 + quad * 8];
#pragma unroll
            for (int mf = 0; mf < 4; mf++)
#pragma unroll
                for (int nf = 0; nf < 2; nf++)
                    acc[mf][nf] = __builtin_amdgcn_mfma_f32_16x16x32_bf16(a[mf], b[nf], acc[mf][nf], 0, 0, 0);
        }
        __syncthreads();
        if (more) {
            *(v8bf*)&As[sr][scb] = pa0; *(v8bf*)&As[sr][scb + 8] = pa1;
            *(v8bf*)&Bs[sr][scb] = pb0; *(v8bf*)&Bs[sr][scb + 8] = pb1;
        }
    }
#pragma unroll
    for (int mf = 0; mf < 4; mf++)
#pragma unroll
        for (int nf = 0; nf < 2; nf++)
#pragma unroll
            for (int r = 0; r < 4; r++) {
                int row = bm + wm + mf * 16 + quad * 4 + r;
                int col = bn + wn + nf * 16 + l16;
                C[(size_t)row * N + col] = acc[mf][nf][r];
            }
}

// ---------------------------------------------------------------------------
// Flash v6: same split-K leveling as v5, but 512 threads (8 waves x 16 q-rows)
// for 16 waves/CU occupancy (was 8), scores kept in log2 domain (exp2f, scale
// folded with log2e), s_setprio(1) around MFMA clusters.
//   piece 0: (qb=bx,    z=0)  key-tiles [0, ceil(T/2))
//   piece 1: (qb=31-bx, z=1)  key-tiles [ceil(T/2), T)       (T = qb+1)
// Unnormalized partials (bf16 O, f32 m/l in log2 units) per z.
// ---------------------------------------------------------------------------
__global__ __launch_bounds__(512, 4) void flash6(const bf16* __restrict__ Q,
                                                 const bf16* __restrict__ Kb,
                                                 const bf16* __restrict__ Vtg,
                                                 bf16* __restrict__ O0,
                                                 bf16* __restrict__ O1,
                                                 float* __restrict__ ML) {
    __shared__ bf16 Ks[128][68];
    __shared__ bf16 Vt[64][132];
    __shared__ bf16 Ps[128][68];
    const int h = blockIdx.y, kvh = h >> 2;
    const int bx = blockIdx.x;
    const int tid = threadIdx.x;
    const int w = tid >> 6, lane = tid & 63;      // w = 0..7
    const int quad = lane >> 4, l16 = lane & 15;
    const int krow = tid >> 2, kcb = (tid & 3) * 16;   // K stage: 128 rows x 64 cols
    const int vr = tid >> 3, vcb = (tid & 7) * 16;     // V stage: 64 rows x 128 cols

    for (int p = 0; p < 2; p++) {
        const int qb = p ? (31 - bx) : bx;
        const int T = qb + 1;
        const int k0 = p ? ((T + 1) >> 1) : 0;
        const int k1 = p ? T : ((T + 1) >> 1);
        bf16* Op = p ? O1 : O0;
        float* mlp = ML + (size_t)(p * NHEADS + h) * L_SEQ * 2;

        if (k0 >= k1) {   // empty piece (bx=31, p=1): zero partial
            for (int i = tid; i < 128 * 64; i += 512) {
                int rr = i >> 6, cc = i & 63;
                Op[(size_t)(qb * 128 + rr) * DMODEL + h * DH + cc] = (bf16)0.f;
            }
            if (tid < 128) {
                mlp[(qb * 128 + tid) * 2 + 0] = NEG_BIG;
                mlp[(qb * 128 + tid) * 2 + 1] = 0.f;
            }
            continue;   // block-uniform
        }

        v8bf qf[2];
#pragma unroll
        for (int kf = 0; kf < 2; kf++)
            qf[kf] = *(const v8bf*)&Q[(size_t)(qb * 128 + w * 16 + l16) * DMODEL
                                      + h * DH + kf * 32 + quad * 8];

        f32x4 oacc[4];
#pragma unroll
        for (int d = 0; d < 4; d++) oacc[d] = (f32x4){0.f, 0.f, 0.f, 0.f};
        float m_i[4], l_i[4];
#pragma unroll
        for (int r = 0; r < 4; r++) { m_i[r] = NEG_BIG; l_i[r] = 0.f; }

        v8bf kreg[2], vreg[2];
        {   // stage tile k0
            const bf16* ks = &Kb[(size_t)(k0 * 128 + krow) * 256 + kvh * DH + kcb];
            const bf16* vs = &Vtg[(size_t)(kvh * DH + vr) * L_SEQ + k0 * 128 + vcb];
            kreg[0] = *(const v8bf*)ks; kreg[1] = *(const v8bf*)(ks + 8);
            vreg[0] = *(const v8bf*)vs; vreg[1] = *(const v8bf*)(vs + 8);
            __syncthreads();   // prior piece's LDS reads complete
            *(v8bf*)&Ks[krow][kcb] = kreg[0]; *(v8bf*)&Ks[krow][kcb + 8] = kreg[1];
            *(v8bf*)&Vt[vr][vcb] = vreg[0];   *(v8bf*)&Vt[vr][vcb + 8] = vreg[1];
        }

        for (int kb = k0; kb < k1; kb++) {
            __syncthreads();
            if (kb + 1 < k1) {
                const bf16* ks = &Kb[(size_t)((kb + 1) * 128 + krow) * 256 + kvh * DH + kcb];
                const bf16* vs = &Vtg[(size_t)(kvh * DH + vr) * L_SEQ + (kb + 1) * 128 + vcb];
                kreg[0] = *(const v8bf*)ks; kreg[1] = *(const v8bf*)(ks + 8);
                vreg[0] = *(const v8bf*)vs; vreg[1] = *(const v8bf*)(vs + 8);
            }

            f32x4 s[8];
            __builtin_amdgcn_s_setprio(1);
#pragma unroll
            for (int n = 0; n < 8; n++) {
                v8bf b0 = *(v8bf*)&Ks[n * 16 + l16][quad * 8];
                v8bf b1 = *(v8bf*)&Ks[n * 16 + l16][32 + quad * 8];
                s[n] = (f32x4){0.f, 0.f, 0.f, 0.f};
                s[n] = __builtin_amdgcn_mfma_f32_16x16x32_bf16(qf[0], b0, s[n], 0, 0, 0);
                s[n] = __builtin_amdgcn_mfma_f32_16x16x32_bf16(qf[1], b1, s[n], 0, 0, 0);
            }
            __builtin_amdgcn_s_setprio(0);

            if (kb == qb) {
                int rbase = qb * 128 + w * 16 + quad * 4;
#pragma unroll
                for (int n = 0; n < 8; n++) {
                    int colg = kb * 128 + n * 16 + l16;
#pragma unroll
                    for (int r = 0; r < 4; r++)
                        s[n][r] = (colg <= rbase + r) ? s[n][r] * SCL2 : NEG_BIG;
                }
            } else {
#pragma unroll
                for (int n = 0; n < 8; n++)
#pragma unroll
                    for (int r = 0; r < 4; r++) s[n][r] *= SCL2;
            }

            float mx[4];
#pragma unroll
            for (int r = 0; r < 4; r++) {
                float m0 = s[0][r];
#pragma unroll
                for (int n = 1; n < 8; n++) m0 = fmaxf(m0, s[n][r]);
                mx[r] = m0;
            }
#pragma unroll
            for (int off = 1; off < 16; off <<= 1)
#pragma unroll
                for (int r = 0; r < 4; r++)
                    mx[r] = fmaxf(mx[r], __shfl_xor(mx[r], off));

            float alpha[4], mnew[4], rs[4];
#pragma unroll
            for (int r = 0; r < 4; r++) {
                mnew[r]  = fmaxf(m_i[r], mx[r]);
                alpha[r] = exp2f(m_i[r] - mnew[r]);
                rs[r] = 0.f;
            }
#pragma unroll
            for (int n = 0; n < 8; n++)
#pragma unroll
                for (int r = 0; r < 4; r++) {
                    float pv = exp2f(s[n][r] - mnew[r]);
                    s[n][r] = pv;
                    rs[r] += pv;
                }
#pragma unroll
            for (int off = 1; off < 16; off <<= 1)
#pragma unroll
                for (int r = 0; r < 4; r++) rs[r] += __shfl_xor(rs[r], off);
#pragma unroll
            for (int r = 0; r < 4; r++) {
                l_i[r] = l_i[r] * alpha[r] + rs[r];
                m_i[r] = mnew[r];
            }
#pragma unroll
            for (int d = 0; d < 4; d++)
#pragma unroll
                for (int r = 0; r < 4; r++) oacc[d][r] *= alpha[r];

#pragma unroll
            for (int half = 0; half < 2; half++) {
#pragma unroll
                for (int n = 0; n < 4; n++)
#pragma unroll
                    for (int r = 0; r < 4; r++)
                        Ps[w * 16 + quad * 4 + r][n * 16 + l16] = (bf16)s[half * 4 + n][r];
                __builtin_amdgcn_s_setprio(1);
#pragma unroll
                for (int kf = 0; kf < 2; kf++) {
                    v8bf pa = *(v8bf*)&Ps[w * 16 + l16][kf * 32 + quad * 8];
#pragma unroll
                    for (int d = 0; d < 4; d++) {
                        v8bf vb = *(v8bf*)&Vt[d * 16 + l16][half * 64 + kf * 32 + quad * 8];
                        oacc[d] = __builtin_amdgcn_mfma_f32_16x16x32_bf16(pa, vb, oacc[d], 0, 0, 0);
                    }
                }
                __builtin_amdgcn_s_setprio(0);
            }

            __syncthreads();
            if (kb + 1 < k1) {
                *(v8bf*)&Ks[krow][kcb] = kreg[0]; *(v8bf*)&Ks[krow][kcb + 8] = kreg[1];
                *(v8bf*)&Vt[vr][vcb] = vreg[0];   *(v8bf*)&Vt[vr][vcb + 8] = vreg[1];
            }
        }

        // ---- unnormalized partial write ----
#pragma unroll
        for (int d = 0; d < 4; d++)
#pragma unroll
            for (int r = 0; r < 4; r++) {
                int row = qb * 128 + w * 16 + quad * 4 + r;
                Op[(size_t)row * DMODEL + h * DH + d * 16 + l16] = (bf16)oacc[d][r];
            }
        if (l16 == 0) {
#pragma unroll
            for (int r = 0; r < 4; r++) {
                int row = qb * 128 + w * 16 + quad * 4 + r;
                mlp[row * 2 + 0] = m_i[r];
                mlp[row * 2 + 1] = l_i[r];
            }
        }
    }
}

// ---------------------------------------------------------------------------
// Combine the two split-K partials into normalized Attn (bf16).
// m values are in log2 domain (scores folded with log2e) -> exp2f here.
// ---------------------------------------------------------------------------
__global__ void combine(const bf16* __restrict__ O0, const bf16* __restrict__ O1,
                        const float* __restrict__ ML, bf16* __restrict__ Attn) {
    int gid = blockIdx.x * 256 + threadIdx.x;
    int row = gid >> 8;
    int cg = (gid & 255) * 4;
    int h = cg >> 6;
    const float* ml0 = ML + ((size_t)h * L_SEQ + row) * 2;
    const float* ml1 = ML + ((size_t)(NHEADS + h) * L_SEQ + row) * 2;
    float m0 = ml0[0], l0 = ml0[1], m1 = ml1[0], l1 = ml1[1];
    float m = fmaxf(m0, m1);
    float a0 = exp2f(m0 - m), a1 = exp2f(m1 - m);
    float inv = 1.f / (a0 * l0 + a1 * l1);
    v4bf o0 = *(const v4bf*)&O0[(size_t)row * DMODEL + cg];
    v4bf o1 = *(const v4bf*)&O1[(size_t)row * DMODEL + cg];
    v4bf res;
#pragma unroll
    for (int j = 0; j < 4; j++)
        res[j] = (bf16)((a0 * (float)o0[j] + a1 * (float)o1[j]) * inv);
    *(v4bf*)&Attn[(size_t)row * DMODEL + cg] = res;
}

// ---------------------------------------------------------------------------
extern "C" void kernel_launch(void* const* d_in, const int* in_sizes, int n_in,
                              void* d_out, int out_size, void* d_ws, size_t ws_size,
                              hipStream_t stream) {
    const float* x  = (const float*)d_in[0];
    const float* Wq = (const float*)d_in[1];
    const float* Wk = (const float*)d_in[2];
    const float* Wv = (const float*)d_in[3];
    const float* Wo = (const float*)d_in[4];
    const int*   tp = (const int*)d_in[5];
    float* out = (float*)d_out;

    bf16*  xb    = (bf16*)d_ws;               // 4,194,304 (reused as Attn)
    bf16*  wqkvb = xb    + 4194304;           // 1,572,864
    bf16*  wob   = wqkvb + 1572864;           // 1,048,576
    bf16*  Qb    = wob   + 1048576;           // 4,194,304
    bf16*  Kb    = Qb    + 4194304;           // 1,048,576  [4096][256]
    bf16*  Vtg   = Kb    + 1048576;           // 1,048,576  [256][4096]
    float* MLf   = (float*)(Vtg + 1048576);   // 262,144 f32
    bf16*  Attn  = xb;
    bf16*  O0    = (bf16*)d_out;              // partial z=0 (bf16, 8.4 MB)
    bf16*  O1    = O0 + 4194304;              // partial z=1

    convert_all<<<6656, 256, 0, stream>>>(x, Wq, Wk, Wv, Wo, xb, wqkvb, wob);
    gemm_qkv<<<dim3(12, 32), 512, 0, stream>>>(xb, wqkvb, Qb, Kb, Vtg, tp);
    flash6<<<dim3(32, NHEADS), 512, 0, stream>>>(Qb, Kb, Vtg, O0, O1, MLf);
    combine<<<4096, 256, 0, stream>>>(O0, O1, MLf, Attn);
    gemm_out<<<dim3(8, 32), 512, 0, stream>>>(Attn, wob, out);
}

// Round 2
// 206.319 us; speedup vs baseline: 1.1986x; 1.1986x over previous
//
#include <hip/hip_runtime.h>
#include <hip/hip_bf16.h>
#include <math.h>

typedef __bf16 bf16;
typedef __bf16 v8bf __attribute__((ext_vector_type(8)));
typedef __bf16 v4bf __attribute__((ext_vector_type(4)));
typedef __bf16 v2bf __attribute__((ext_vector_type(2)));
typedef float f32x4 __attribute__((ext_vector_type(4)));
typedef float f32x16 __attribute__((ext_vector_type(16)));

#define L_SEQ 4096
#define DMODEL 1024
#define NHEADS 16
#define DH 64
#define NEG_BIG (-1e30f)
#define LN1E4_64 0.14391156f   // ln(10000)/64
#define SCL2 0.18033688f       // 0.125 * log2(e): scores scaled into log2 domain

static __device__ __forceinline__ unsigned pkbf(float x, float y) {
    v2bf t; t[0] = (bf16)x; t[1] = (bf16)y;
    return __builtin_bit_cast(unsigned, t);
}

// ---------------------------------------------------------------------------
// One-shot f32 -> bf16 conversion. Layout: xb[4096*1024], wqkvb[1536*1024]
// (Wq rows 0..1023, Wk rows 1024..1279, Wv rows 1280..1535), wob[1024*1024].
// ---------------------------------------------------------------------------
__global__ void convert_all(const float* __restrict__ x, const float* __restrict__ wq,
                            const float* __restrict__ wk, const float* __restrict__ wv,
                            const float* __restrict__ wo,
                            bf16* __restrict__ xb, bf16* __restrict__ wqkvb,
                            bf16* __restrict__ wob) {
    int i = (blockIdx.x * 256 + threadIdx.x) * 4;
    const float* src;
    bf16* dst;
    if (i < 4194304)      { src = x  + i;             dst = xb    + i; }
    else if (i < 5242880) { src = wq + (i - 4194304); dst = wqkvb + (i - 4194304); }
    else if (i < 5505024) { src = wk + (i - 5242880); dst = wqkvb + 1048576 + (i - 5242880); }
    else if (i < 5767168) { src = wv + (i - 5505024); dst = wqkvb + 1310720 + (i - 5505024); }
    else                  { src = wo + (i - 5767168); dst = wob   + (i - 5767168); }
    f32x4 v = *(const f32x4*)src;
    v4bf r;
#pragma unroll
    for (int j = 0; j < 4; j++) r[j] = (bf16)v[j];
    *(v4bf*)dst = r;
}

// ---------------------------------------------------------------------------
// Fused QKV projection: C[4096][1536] = x @ [Wq;Wk;Wv]^T, 128x128 tiles,
// 512 threads (8 waves, 2 waves/SIMD), register-prefetch pipeline.
// Epilogue by column region: Q (+RoPE) -> Qb, K (+RoPE) -> Kb, V -> Vtg^T.
// ---------------------------------------------------------------------------
__global__ __launch_bounds__(512) void gemm_qkv(const bf16* __restrict__ A,
                                                const bf16* __restrict__ W,
                                                bf16* __restrict__ Qb,
                                                bf16* __restrict__ Kb,
                                                bf16* __restrict__ Vtg,
                                                const int* __restrict__ tp) {
    __shared__ bf16 As[128][68];
    __shared__ bf16 Bs[128][68];
    const int K = 1024;
    const int tid = threadIdx.x;
    const int w = tid >> 6, lane = tid & 63;
    const int quad = lane >> 4, l16 = lane & 15;
    const int wm = (w & 1) * 64, wn = (w >> 1) * 32;
    const int bm = blockIdx.y * 128, bn = blockIdx.x * 128;

    f32x4 acc[4][2];
#pragma unroll
    for (int mf = 0; mf < 4; mf++)
#pragma unroll
        for (int nf = 0; nf < 2; nf++) acc[mf][nf] = (f32x4){0.f, 0.f, 0.f, 0.f};

    const int sr = tid >> 2;          // 0..127
    const int scb = (tid & 3) * 16;   // 0,16,32,48

    v8bf pa0, pa1, pb0, pb1;
    {   // prologue: stage tile kt=0
        const bf16* ap = &A[(size_t)(bm + sr) * K + scb];
        const bf16* bp = &W[(size_t)(bn + sr) * K + scb];
        pa0 = *(const v8bf*)ap; pa1 = *(const v8bf*)(ap + 8);
        pb0 = *(const v8bf*)bp; pb1 = *(const v8bf*)(bp + 8);
        *(v8bf*)&As[sr][scb] = pa0; *(v8bf*)&As[sr][scb + 8] = pa1;
        *(v8bf*)&Bs[sr][scb] = pb0; *(v8bf*)&Bs[sr][scb + 8] = pb1;
    }

    for (int kt = 0; kt < K; kt += 64) {
        __syncthreads();
        const bool more = (kt + 64) < K;
        if (more) {
            const bf16* ap = &A[(size_t)(bm + sr) * K + kt + 64 + scb];
            const bf16* bp = &W[(size_t)(bn + sr) * K + kt + 64 + scb];
            pa0 = *(const v8bf*)ap; pa1 = *(const v8bf*)(ap + 8);
            pb0 = *(const v8bf*)bp; pb1 = *(const v8bf*)(bp + 8);
        }
#pragma unroll
        for (int kf = 0; kf < 2; kf++) {
            v8bf a[4], b[2];
#pragma unroll
            for (int mf = 0; mf < 4; mf++) a[mf] = *(v8bf*)&As[wm + mf * 16 + l16][kf * 32 + quad * 8];
#pragma unroll
            for (int nf = 0; nf < 2; nf++) b[nf] = *(v8bf*)&Bs[wn + nf * 16 + l16][kf * 32 + quad * 8];
#pragma unroll
            for (int mf = 0; mf < 4; mf++)
#pragma unroll
                for (int nf = 0; nf < 2; nf++)
                    acc[mf][nf] = __builtin_amdgcn_mfma_f32_16x16x32_bf16(a[mf], b[nf], acc[mf][nf], 0, 0, 0);
        }
        __syncthreads();
        if (more) {
            *(v8bf*)&As[sr][scb] = pa0; *(v8bf*)&As[sr][scb + 8] = pa1;
            *(v8bf*)&Bs[sr][scb] = pb0; *(v8bf*)&Bs[sr][scb + 8] = pb1;
        }
    }

    if (bn < 1024) {          // ---- Q region: RoPE, store Qb[row][col] ----
#pragma unroll
        for (int mf = 0; mf < 4; mf++) {
            int pos_[4];
#pragma unroll
            for (int r = 0; r < 4; r++) pos_[r] = tp[bm + wm + mf * 16 + quad * 4 + r];
#pragma unroll
            for (int nf = 0; nf < 2; nf++) {
                const int col = bn + wn + nf * 16 + l16;
                float fr = __expf(-(float)((col & 63) & ~1) * LN1E4_64);
#pragma unroll
                for (int r = 0; r < 4; r++) {
                    float v = acc[mf][nf][r];
                    float sn, cs;
                    __sincosf((float)pos_[r] * fr, &sn, &cs);
                    float p = __shfl_xor(v, 1);
                    float res = (l16 & 1) ? (p * sn + v * cs) : (v * cs - p * sn);
                    int row = bm + wm + mf * 16 + quad * 4 + r;
                    Qb[(size_t)row * DMODEL + col] = (bf16)res;
                }
            }
        }
    } else if (bn < 1280) {   // ---- K region: RoPE, store Kb[row][kcol] ----
#pragma unroll
        for (int mf = 0; mf < 4; mf++) {
            int pos_[4];
#pragma unroll
            for (int r = 0; r < 4; r++) pos_[r] = tp[bm + wm + mf * 16 + quad * 4 + r];
#pragma unroll
            for (int nf = 0; nf < 2; nf++) {
                const int kcol = bn - 1024 + wn + nf * 16 + l16;
                float fr = __expf(-(float)((kcol & 63) & ~1) * LN1E4_64);
#pragma unroll
                for (int r = 0; r < 4; r++) {
                    float v = acc[mf][nf][r];
                    float sn, cs;
                    __sincosf((float)pos_[r] * fr, &sn, &cs);
                    float p = __shfl_xor(v, 1);
                    float res = (l16 & 1) ? (p * sn + v * cs) : (v * cs - p * sn);
                    int row = bm + wm + mf * 16 + quad * 4 + r;
                    Kb[(size_t)row * 256 + kcol] = (bf16)res;
                }
            }
        }
    } else {                  // ---- V region: transposed store Vtg[vcol][row] ----
#pragma unroll
        for (int mf = 0; mf < 4; mf++)
#pragma unroll
            for (int nf = 0; nf < 2; nf++) {
                v4bf pk;
#pragma unroll
                for (int r = 0; r < 4; r++) pk[r] = (bf16)acc[mf][nf][r];
                int vcol = bn - 1280 + wn + nf * 16 + l16;
                int row = bm + wm + mf * 16 + quad * 4;
                *(v4bf*)&Vtg[(size_t)vcol * L_SEQ + row] = pk;
            }
    }
}

// ---------------------------------------------------------------------------
// Output projection: out[4096][1024] = Attn @ Wo^T, f32 out. Same engine.
// ---------------------------------------------------------------------------
__global__ __launch_bounds__(512) void gemm_out(const bf16* __restrict__ A,
                                                const bf16* __restrict__ W,
                                                float* __restrict__ C) {
    __shared__ bf16 As[128][68];
    __shared__ bf16 Bs[128][68];
    const int K = 1024, N = 1024;
    const int tid = threadIdx.x;
    const int w = tid >> 6, lane = tid & 63;
    const int quad = lane >> 4, l16 = lane & 15;
    const int wm = (w & 1) * 64, wn = (w >> 1) * 32;
    const int bm = blockIdx.y * 128, bn = blockIdx.x * 128;

    f32x4 acc[4][2];
#pragma unroll
    for (int mf = 0; mf < 4; mf++)
#pragma unroll
        for (int nf = 0; nf < 2; nf++) acc[mf][nf] = (f32x4){0.f, 0.f, 0.f, 0.f};

    const int sr = tid >> 2;
    const int scb = (tid & 3) * 16;

    v8bf pa0, pa1, pb0, pb1;
    {
        const bf16* ap = &A[(size_t)(bm + sr) * K + scb];
        const bf16* bp = &W[(size_t)(bn + sr) * K + scb];
        pa0 = *(const v8bf*)ap; pa1 = *(const v8bf*)(ap + 8);
        pb0 = *(const v8bf*)bp; pb1 = *(const v8bf*)(bp + 8);
        *(v8bf*)&As[sr][scb] = pa0; *(v8bf*)&As[sr][scb + 8] = pa1;
        *(v8bf*)&Bs[sr][scb] = pb0; *(v8bf*)&Bs[sr][scb + 8] = pb1;
    }

    for (int kt = 0; kt < K; kt += 64) {
        __syncthreads();
        const bool more = (kt + 64) < K;
        if (more) {
            const bf16* ap = &A[(size_t)(bm + sr) * K + kt + 64 + scb];
            const bf16* bp = &W[(size_t)(bn + sr) * K + kt + 64 + scb];
            pa0 = *(const v8bf*)ap; pa1 = *(const v8bf*)(ap + 8);
            pb0 = *(const v8bf*)bp; pb1 = *(const v8bf*)(bp + 8);
        }
#pragma unroll
        for (int kf = 0; kf < 2; kf++) {
            v8bf a[4], b[2];
#pragma unroll
            for (int mf = 0; mf < 4; mf++) a[mf] = *(v8bf*)&As[wm + mf * 16 + l16][kf * 32 + quad * 8];
#pragma unroll
            for (int nf = 0; nf < 2; nf++) b[nf] = *(v8bf*)&Bs[wn + nf * 16 + l16][kf * 32 + quad * 8];
#pragma unroll
            for (int mf = 0; mf < 4; mf++)
#pragma unroll
                for (int nf = 0; nf < 2; nf++)
                    acc[mf][nf] = __builtin_amdgcn_mfma_f32_16x16x32_bf16(a[mf], b[nf], acc[mf][nf], 0, 0, 0);
        }
        __syncthreads();
        if (more) {
            *(v8bf*)&As[sr][scb] = pa0; *(v8bf*)&As[sr][scb + 8] = pa1;
            *(v8bf*)&Bs[sr][scb] = pb0; *(v8bf*)&Bs[sr][scb + 8] = pb1;
        }
    }
#pragma unroll
    for (int mf = 0; mf < 4; mf++)
#pragma unroll
        for (int nf = 0; nf < 2; nf++)
#pragma unroll
            for (int r = 0; r < 4; r++) {
                int row = bm + wm + mf * 16 + quad * 4 + r;
                int col = bn + wn + nf * 16 + l16;
                C[(size_t)row * N + col] = acc[mf][nf][r];
            }
}

// ---------------------------------------------------------------------------
// Flash v7: swapped-operand 32x32 layout. 256 threads, 4 waves x 32 q-rows,
// KVBLK=128, same split-K leveling as v5.
//   QK^T: S^T = mfma_32x32x16(K_frag, Q_frag) -> lane&31 = q-row.
//   Softmax: per-lane reduce (63 ops) + ONE shfl_xor(32). No shuffle trees.
//   P: in-register bf16 packs + permlane32_swap -> PV B-operand. No Ps LDS.
//   PV: O^T = mfma(V^T_frag, P^T_frag) -> alpha rescale is lane-local.
//   Epilogue: transpose O^T through Ks LDS for coalesced 16B stores.
// ---------------------------------------------------------------------------
__global__ __launch_bounds__(256, 2) void flash7(const bf16* __restrict__ Q,
                                                 const bf16* __restrict__ Kb,
                                                 const bf16* __restrict__ Vtg,
                                                 bf16* __restrict__ O0,
                                                 bf16* __restrict__ O1,
                                                 float* __restrict__ ML) {
    __shared__ bf16 Ks[128][68];
    __shared__ bf16 Vt[64][132];
    const int h = blockIdx.y, kvh = h >> 2;
    const int bx = blockIdx.x;
    const int tid = threadIdx.x;
    const int w = tid >> 6, lane = tid & 63;
    const int l32 = lane & 31, hi = lane >> 5;
    const int krow = tid >> 1, kcb = (tid & 1) * 32;
    const int vr = tid >> 2, vcb = (tid & 3) * 32;

    for (int p = 0; p < 2; p++) {
        const int qb = p ? (31 - bx) : bx;
        const int T = qb + 1;
        const int k0 = p ? ((T + 1) >> 1) : 0;
        const int k1 = p ? T : ((T + 1) >> 1);
        bf16* Op = p ? O1 : O0;
        float* mlp = ML + (size_t)(p * NHEADS + h) * L_SEQ * 2;

        if (k0 >= k1) {   // empty piece (bx=31, p=1): zero partial
            for (int i = tid; i < 128 * 64; i += 256) {
                int rr = i >> 6, cc = i & 63;
                Op[(size_t)(qb * 128 + rr) * DMODEL + h * DH + cc] = (bf16)0.f;
            }
            if (tid < 128) {
                mlp[(qb * 128 + tid) * 2 + 0] = NEG_BIG;
                mlp[(qb * 128 + tid) * 2 + 1] = 0.f;
            }
            continue;   // block-uniform
        }

        const int qrow = qb * 128 + w * 32 + l32;
        v8bf qf[4];
#pragma unroll
        for (int d16 = 0; d16 < 4; d16++)
            qf[d16] = *(const v8bf*)&Q[(size_t)qrow * DMODEL + h * DH + d16 * 16 + hi * 8];

        f32x16 oaccT[2];
#pragma unroll
        for (int d = 0; d < 2; d++)
#pragma unroll
            for (int r = 0; r < 16; r++) oaccT[d][r] = 0.f;
        float m_i = NEG_BIG, l_i = 0.f;

        v8bf kreg[4], vreg[4];
        {   // stage tile k0
            const bf16* ks = &Kb[(size_t)(k0 * 128 + krow) * 256 + kvh * DH + kcb];
            const bf16* vs = &Vtg[(size_t)(kvh * DH + vr) * L_SEQ + k0 * 128 + vcb];
#pragma unroll
            for (int u = 0; u < 4; u++) { kreg[u] = *(const v8bf*)&ks[8 * u]; vreg[u] = *(const v8bf*)&vs[8 * u]; }
            __syncthreads();   // prior piece's LDS reads complete
#pragma unroll
            for (int u = 0; u < 4; u++) { *(v8bf*)&Ks[krow][kcb + 8 * u] = kreg[u]; *(v8bf*)&Vt[vr][vcb + 8 * u] = vreg[u]; }
        }

        for (int kb = k0; kb < k1; kb++) {
            __syncthreads();
            if (kb + 1 < k1) {
                const bf16* ks = &Kb[(size_t)((kb + 1) * 128 + krow) * 256 + kvh * DH + kcb];
                const bf16* vs = &Vtg[(size_t)(kvh * DH + vr) * L_SEQ + (kb + 1) * 128 + vcb];
#pragma unroll
                for (int u = 0; u < 4; u++) { kreg[u] = *(const v8bf*)&ks[8 * u]; vreg[u] = *(const v8bf*)&vs[8 * u]; }
            }

            // ---- QK^T (swapped): s[n] = S^T[key=n*32+...][q=lane&31] ----
            f32x16 s[4];
            __builtin_amdgcn_s_setprio(1);
#pragma unroll
            for (int n = 0; n < 4; n++) {
#pragma unroll
                for (int r = 0; r < 16; r++) s[n][r] = 0.f;
#pragma unroll
                for (int d16 = 0; d16 < 4; d16++) {
                    v8bf av = *(v8bf*)&Ks[n * 32 + l32][d16 * 16 + hi * 8];
                    s[n] = __builtin_amdgcn_mfma_f32_32x32x16_bf16(av, qf[d16], s[n], 0, 0, 0);
                }
            }
            __builtin_amdgcn_s_setprio(0);

            // ---- scale (+causal mask on diag) ----
            if (kb == qb) {
#pragma unroll
                for (int n = 0; n < 4; n++) {
                    int kbase = kb * 128 + n * 32 + 4 * hi;
#pragma unroll
                    for (int r = 0; r < 16; r++) {
                        int key = kbase + (r & 3) + 8 * (r >> 2);
                        s[n][r] = (key <= qrow) ? s[n][r] * SCL2 : NEG_BIG;
                    }
                }
            } else {
#pragma unroll
                for (int n = 0; n < 4; n++)
#pragma unroll
                    for (int r = 0; r < 16; r++) s[n][r] *= SCL2;
            }

            // ---- online softmax: per-lane reduce + one cross-half shuffle ----
            float mx = s[0][0];
#pragma unroll
            for (int n = 0; n < 4; n++)
#pragma unroll
                for (int r = 0; r < 16; r++) mx = fmaxf(mx, s[n][r]);
            mx = fmaxf(mx, __shfl_xor(mx, 32));

            float mnew = fmaxf(m_i, mx);
            float alpha = exp2f(m_i - mnew);
            float rs = 0.f;
#pragma unroll
            for (int n = 0; n < 4; n++)
#pragma unroll
                for (int r = 0; r < 16; r++) {
                    float pv = exp2f(s[n][r] - mnew);
                    s[n][r] = pv;
                    rs += pv;
                }
            rs += __shfl_xor(rs, 32);
            l_i = l_i * alpha + rs;
            m_i = mnew;
#pragma unroll
            for (int d = 0; d < 2; d++)
#pragma unroll
                for (int r = 0; r < 16; r++) oaccT[d][r] *= alpha;

            // ---- P pack + swap -> PV (no LDS round-trip) ----
            __builtin_amdgcn_s_setprio(1);
#pragma unroll
            for (int n = 0; n < 4; n++) {
#pragma unroll
                for (int u = 0; u < 2; u++) {
                    const int ro = u * 8;
                    unsigned a0 = pkbf(s[n][ro + 0], s[n][ro + 1]);
                    unsigned a1 = pkbf(s[n][ro + 2], s[n][ro + 3]);
                    unsigned b0 = pkbf(s[n][ro + 4], s[n][ro + 5]);
                    unsigned b1 = pkbf(s[n][ro + 6], s[n][ro + 7]);
#if __has_builtin(__builtin_amdgcn_permlane32_swap)
                    auto s0 = __builtin_amdgcn_permlane32_swap(a0, b0, false, false);
                    auto s1 = __builtin_amdgcn_permlane32_swap(a1, b1, false, false);
                    unsigned w0 = s0[0], w2 = s0[1], w1 = s1[0], w3 = s1[1];
#else
                    unsigned t0 = hi ? a0 : b0;
                    unsigned r0 = __shfl_xor(t0, 32);
                    unsigned w0 = hi ? r0 : a0, w2 = hi ? b0 : r0;
                    unsigned t1 = hi ? a1 : b1;
                    unsigned r1 = __shfl_xor(t1, 32);
                    unsigned w1 = hi ? r1 : a1, w3 = hi ? b1 : r1;
#endif
                    union { unsigned uu[4]; v8bf v; } pf;
                    pf.uu[0] = w0; pf.uu[1] = w1; pf.uu[2] = w2; pf.uu[3] = w3;
                    const int t = n * 2 + u;
#pragma unroll
                    for (int dblk = 0; dblk < 2; dblk++) {
                        v8bf av = *(v8bf*)&Vt[dblk * 32 + l32][t * 16 + hi * 8];
                        oaccT[dblk] = __builtin_amdgcn_mfma_f32_32x32x16_bf16(av, pf.v, oaccT[dblk], 0, 0, 0);
                    }
                }
            }
            __builtin_amdgcn_s_setprio(0);

            __syncthreads();
            if (kb + 1 < k1) {
#pragma unroll
                for (int u = 0; u < 4; u++) { *(v8bf*)&Ks[krow][kcb + 8 * u] = kreg[u]; *(v8bf*)&Vt[vr][vcb + 8 * u] = vreg[u]; }
            }
        }

        // ---- epilogue: transpose O^T through Ks, coalesced partial write ----
        __syncthreads();   // all waves done reading Ks for this piece
#pragma unroll
        for (int dblk = 0; dblk < 2; dblk++)
#pragma unroll
            for (int r = 0; r < 16; r++) {
                int d = dblk * 32 + (r & 3) + 8 * (r >> 2) + 4 * hi;
                Ks[w * 32 + l32][d] = (bf16)oaccT[dblk][r];
            }
        asm volatile("s_waitcnt lgkmcnt(0)" ::: "memory");
        __builtin_amdgcn_sched_barrier(0);
#pragma unroll
        for (int i = 0; i < 4; i++) {
            int cc = (lane & 1) * 32 + i * 8;
            int rr = w * 32 + (lane >> 1);
            v8bf ov = *(v8bf*)&Ks[rr][cc];
            *(v8bf*)&Op[(size_t)(qb * 128 + rr) * DMODEL + h * DH + cc] = ov;
        }
        if (hi == 0) {
            mlp[qrow * 2 + 0] = m_i;
            mlp[qrow * 2 + 1] = l_i;
        }
    }
}

// ---------------------------------------------------------------------------
// Combine the two split-K partials into normalized Attn (bf16).
// m values are in log2 domain (scores folded with log2e) -> exp2f here.
// ---------------------------------------------------------------------------
__global__ void combine(const bf16* __restrict__ O0, const bf16* __restrict__ O1,
                        const float* __restrict__ ML, bf16* __restrict__ Attn) {
    int gid = blockIdx.x * 256 + threadIdx.x;
    int row = gid >> 8;
    int cg = (gid & 255) * 4;
    int h = cg >> 6;
    const float* ml0 = ML + ((size_t)h * L_SEQ + row) * 2;
    const float* ml1 = ML + ((size_t)(NHEADS + h) * L_SEQ + row) * 2;
    float m0 = ml0[0], l0 = ml0[1], m1 = ml1[0], l1 = ml1[1];
    float m = fmaxf(m0, m1);
    float a0 = exp2f(m0 - m), a1 = exp2f(m1 - m);
    float inv = 1.f / (a0 * l0 + a1 * l1);
    v4bf o0 = *(const v4bf*)&O0[(size_t)row * DMODEL + cg];
    v4bf o1 = *(const v4bf*)&O1[(size_t)row * DMODEL + cg];
    v4bf res;
#pragma unroll
    for (int j = 0; j < 4; j++)
        res[j] = (bf16)((a0 * (float)o0[j] + a1 * (float)o1[j]) * inv);
    *(v4bf*)&Attn[(size_t)row * DMODEL + cg] = res;
}

// ---------------------------------------------------------------------------
extern "C" void kernel_launch(void* const* d_in, const int* in_sizes, int n_in,
                              void* d_out, int out_size, void* d_ws, size_t ws_size,
                              hipStream_t stream) {
    const float* x  = (const float*)d_in[0];
    const float* Wq = (const float*)d_in[1];
    const float* Wk = (const float*)d_in[2];
    const float* Wv = (const float*)d_in[3];
    const float* Wo = (const float*)d_in[4];
    const int*   tp = (const int*)d_in[5];
    float* out = (float*)d_out;

    bf16*  xb    = (bf16*)d_ws;               // 4,194,304 (reused as Attn)
    bf16*  wqkvb = xb    + 4194304;           // 1,572,864
    bf16*  wob   = wqkvb + 1572864;           // 1,048,576
    bf16*  Qb    = wob   + 1048576;           // 4,194,304
    bf16*  Kb    = Qb    + 4194304;           // 1,048,576  [4096][256]
    bf16*  Vtg   = Kb    + 1048576;           // 1,048,576  [256][4096]
    float* MLf   = (float*)(Vtg + 1048576);   // 262,144 f32
    bf16*  Attn  = xb;
    bf16*  O0    = (bf16*)d_out;              // partial z=0 (bf16, 8.4 MB)
    bf16*  O1    = O0 + 4194304;              // partial z=1

    convert_all<<<6656, 256, 0, stream>>>(x, Wq, Wk, Wv, Wo, xb, wqkvb, wob);
    gemm_qkv<<<dim3(12, 32), 512, 0, stream>>>(xb, wqkvb, Qb, Kb, Vtg, tp);
    flash7<<<dim3(32, NHEADS), 256, 0, stream>>>(Qb, Kb, Vtg, O0, O1, MLf);
    combine<<<4096, 256, 0, stream>>>(O0, O1, MLf, Attn);
    gemm_out<<<dim3(8, 32), 512, 0, stream>>>(Attn, wob, out);
}